// Round 1
// baseline (110.348 us; speedup 1.0000x reference)
//
#include <hip/hip_runtime.h>
#include <hip/hip_bf16.h>

// Sparsemax over rows: z [8192, 8192] f32, a = 1.0.
// tau is found via Michelot's fixed-point iteration (no sort needed):
//   tau_0 = (sum(z) - 1)/D
//   tau_{t+1} = (sum_{z_i > tau_t} z_i - 1) / #{z_i > tau_t}
// Monotone convergent; fixed point satisfies exactly the reference's
// tau = (S_rho - 1)/rho with rho = support size.

#define ROW_D 8192
#define BLOCK 256
#define VPT 32  // values per thread (32 * 256 = 8192)

__global__ __launch_bounds__(BLOCK) void sparsemax_kernel(
    const float* __restrict__ z, float* __restrict__ out) {
    const int row = blockIdx.x;
    const float* zr = z + (size_t)row * ROW_D;
    float* outr = out + (size_t)row * ROW_D;
    const int t = threadIdx.x;
    const int lane = t & 63;
    const int wave = t >> 6;

    // ---- load row into registers, coalesced float4 ----
    float v[VPT];
    const float4* z4 = (const float4*)zr;
#pragma unroll
    for (int j = 0; j < 8; ++j) {
        float4 q = z4[j * BLOCK + t];
        v[j * 4 + 0] = q.x;
        v[j * 4 + 1] = q.y;
        v[j * 4 + 2] = q.z;
        v[j * 4 + 3] = q.w;
    }

    __shared__ float s_sum[4];
    __shared__ float s_cnt[4];

    // ---- initial tau = (sum - 1)/D ----
    float s = 0.f;
#pragma unroll
    for (int j = 0; j < VPT; ++j) s += v[j];
#pragma unroll
    for (int off = 32; off > 0; off >>= 1) s += __shfl_down(s, off, 64);
    if (lane == 0) s_sum[wave] = s;
    __syncthreads();
    float tau = (s_sum[0] + s_sum[1] + s_sum[2] + s_sum[3] - 1.0f) / (float)ROW_D;

    // ---- Michelot fixed-point iterations ----
    for (int it = 0; it < 64; ++it) {
        float ps = 0.f, pc = 0.f;
#pragma unroll
        for (int j = 0; j < VPT; ++j) {
            bool in = v[j] > tau;
            ps += in ? v[j] : 0.f;
            pc += in ? 1.f : 0.f;
        }
#pragma unroll
        for (int off = 32; off > 0; off >>= 1) {
            ps += __shfl_down(ps, off, 64);
            pc += __shfl_down(pc, off, 64);
        }
        __syncthreads();  // previous-iteration reads done before overwrite
        if (lane == 0) {
            s_sum[wave] = ps;
            s_cnt[wave] = pc;
        }
        __syncthreads();
        float S = s_sum[0] + s_sum[1] + s_sum[2] + s_sum[3];
        float k = s_cnt[0] + s_cnt[1] + s_cnt[2] + s_cnt[3];
        float ntau = (S - 1.0f) / k;  // k >= 1 always (max element stays in support)
        if (ntau == tau) break;       // uniform branch: same LDS values on all threads
        tau = ntau;
    }

    // ---- write w = max(z - tau, 0), coalesced float4 ----
    float4* o4 = (float4*)outr;
#pragma unroll
    for (int j = 0; j < 8; ++j) {
        float4 q;
        q.x = fmaxf(v[j * 4 + 0] - tau, 0.f);
        q.y = fmaxf(v[j * 4 + 1] - tau, 0.f);
        q.z = fmaxf(v[j * 4 + 2] - tau, 0.f);
        q.w = fmaxf(v[j * 4 + 3] - tau, 0.f);
        o4[j * BLOCK + t] = q;
    }
}

extern "C" void kernel_launch(void* const* d_in, const int* in_sizes, int n_in,
                              void* d_out, int out_size, void* d_ws, size_t ws_size,
                              hipStream_t stream) {
    const float* z = (const float*)d_in[0];
    float* out = (float*)d_out;
    const int rows = out_size / ROW_D;  // 8192
    sparsemax_kernel<<<rows, BLOCK, 0, stream>>>(z, out);
}

// Round 3
// 99.818 us; speedup vs baseline: 1.1055x; 1.1055x over previous
//
#include <hip/hip_runtime.h>
#include <hip/hip_bf16.h>

// Sparsemax over rows: z [8192, 8192] f32, a = 1.0.
//
// Key analytic bound: sum(w)=1, w>=0  =>  tau in [z_max - 1, z_max], and any
// element <= z_max - 1 is provably OUT of the support. For Gaussian rows only
// ~20/8192 elements survive, so:
//   1. block max-reduce (1 barrier)
//   2. filter survivors into a small LDS buffer (1 barrier)
//   3. wave 0 runs Michelot fixed-point on the tiny candidate set (in-wave
//      shuffle reductions only, no block barriers), broadcasts tau
//   4. all threads write max(z - tau, 0) from registers
// Fallback to full-block Michelot if the candidate buffer overflows
// (pathological near-uniform rows).

#define ROW_D 8192
#define BLOCK 256
#define VPT 32    // 32 * 256 = 8192
#define CAP 1024  // candidate buffer (typical occupancy ~20)

typedef float f32x4 __attribute__((ext_vector_type(4)));

__global__ __launch_bounds__(BLOCK) void sparsemax_kernel(
    const float* __restrict__ z, float* __restrict__ out) {
    const int row = blockIdx.x;
    const f32x4* z4 = (const f32x4*)(z + (size_t)row * ROW_D);
    f32x4* o4 = (f32x4*)(out + (size_t)row * ROW_D);
    const int t = threadIdx.x;
    const int lane = t & 63;
    const int wave = t >> 6;

    __shared__ float s_a[4];
    __shared__ float s_b[4];
    __shared__ float s_cand[CAP];
    __shared__ int s_cnt;
    __shared__ float s_tau;

    // ---- load row into registers, coalesced nontemporal float4 ----
    float v[VPT];
#pragma unroll
    for (int j = 0; j < 8; ++j) {
        f32x4 q = __builtin_nontemporal_load(&z4[j * BLOCK + t]);
        v[j * 4 + 0] = q.x;
        v[j * 4 + 1] = q.y;
        v[j * 4 + 2] = q.z;
        v[j * 4 + 3] = q.w;
    }

    // ---- block max reduction ----
    float m = v[0];
#pragma unroll
    for (int j = 1; j < VPT; ++j) m = fmaxf(m, v[j]);
#pragma unroll
    for (int off = 1; off < 64; off <<= 1) m = fmaxf(m, __shfl_xor(m, off, 64));
    if (t == 0) s_cnt = 0;
    if (lane == 0) s_a[wave] = m;
    __syncthreads();
    const float rmax = fmaxf(fmaxf(s_a[0], s_a[1]), fmaxf(s_a[2], s_a[3]));
    const float thr = rmax - 1.0f;  // tau >= thr provably

    // ---- collect candidates > thr ----
#pragma unroll
    for (int j = 0; j < VPT; ++j) {
        if (v[j] > thr) {
            int idx = atomicAdd(&s_cnt, 1);
            if (idx < CAP) s_cand[idx] = v[j];
        }
    }
    __syncthreads();
    const int cnt = s_cnt;  // uniform across block

    float tau;
    if (cnt <= CAP) {
        // ---- wave 0 solves Michelot on the candidate set ----
        if (wave == 0) {
            float S = 0.f, K = 0.f;
            for (int i = lane; i < cnt; i += 64) {
                S += s_cand[i];
                K += 1.f;
            }
#pragma unroll
            for (int off = 1; off < 64; off <<= 1) {
                S += __shfl_xor(S, off, 64);
                K += __shfl_xor(K, off, 64);
            }
            float tl = (S - 1.f) / K;  // <= tau* (Michelot invariant)
            for (int it = 0; it < 64; ++it) {
                float ps = 0.f, pc = 0.f;
                for (int i = lane; i < cnt; i += 64) {
                    float x = s_cand[i];
                    if (x > tl) {
                        ps += x;
                        pc += 1.f;
                    }
                }
#pragma unroll
                for (int off = 1; off < 64; off <<= 1) {
                    ps += __shfl_xor(ps, off, 64);
                    pc += __shfl_xor(pc, off, 64);
                }
                float nt = (ps - 1.f) / pc;
                if (nt == tl) break;  // uniform within wave
                tl = nt;
            }
            if (lane == 0) s_tau = tl;
        }
        __syncthreads();
        tau = s_tau;
    } else {
        // ---- fallback: full-block Michelot (pathological rows) ----
        float s = 0.f;
#pragma unroll
        for (int j = 0; j < VPT; ++j) s += v[j];
#pragma unroll
        for (int off = 1; off < 64; off <<= 1) s += __shfl_xor(s, off, 64);
        if (lane == 0) s_a[wave] = s;
        __syncthreads();
        tau = (s_a[0] + s_a[1] + s_a[2] + s_a[3] - 1.0f) / (float)ROW_D;
        for (int it = 0; it < 64; ++it) {
            float ps = 0.f, pc = 0.f;
#pragma unroll
            for (int j = 0; j < VPT; ++j) {
                bool in = v[j] > tau;
                ps += in ? v[j] : 0.f;
                pc += in ? 1.f : 0.f;
            }
#pragma unroll
            for (int off = 1; off < 64; off <<= 1) {
                ps += __shfl_xor(ps, off, 64);
                pc += __shfl_xor(pc, off, 64);
            }
            __syncthreads();
            if (lane == 0) {
                s_a[wave] = ps;
                s_b[wave] = pc;
            }
            __syncthreads();
            float S = s_a[0] + s_a[1] + s_a[2] + s_a[3];
            float K = s_b[0] + s_b[1] + s_b[2] + s_b[3];
            float nt = (S - 1.0f) / K;
            if (nt == tau) break;
            tau = nt;
        }
    }

    // ---- write w = max(z - tau, 0), nontemporal float4 ----
#pragma unroll
    for (int j = 0; j < 8; ++j) {
        f32x4 q;
        q.x = fmaxf(v[j * 4 + 0] - tau, 0.f);
        q.y = fmaxf(v[j * 4 + 1] - tau, 0.f);
        q.z = fmaxf(v[j * 4 + 2] - tau, 0.f);
        q.w = fmaxf(v[j * 4 + 3] - tau, 0.f);
        __builtin_nontemporal_store(q, &o4[j * BLOCK + t]);
    }
}

extern "C" void kernel_launch(void* const* d_in, const int* in_sizes, int n_in,
                              void* d_out, int out_size, void* d_ws, size_t ws_size,
                              hipStream_t stream) {
    const float* z = (const float*)d_in[0];
    float* out = (float*)d_out;
    const int rows = out_size / ROW_D;  // 8192
    sparsemax_kernel<<<rows, BLOCK, 0, stream>>>(z, out);
}

// Round 4
// 98.019 us; speedup vs baseline: 1.1258x; 1.0184x over previous
//
#include <hip/hip_runtime.h>
#include <hip/hip_bf16.h>

// Sparsemax over rows: z [8192, 8192] f32, a = 1.0.
//
// Algorithm (no sort): tau in [z_max-1, z_max] analytically, so filter to the
// ~20 candidates > z_max-1, solve Michelot fixed-point on them in one wave,
// broadcast tau, write max(z-tau,0).
//
// R4 change: BLOCK 256->512, VPT 32->16, __launch_bounds__(512,8) to keep
// VGPR <= 64 -> 8 waves/SIMD (32 waves/CU) for 2x memory-level parallelism.

#define ROW_D 8192
#define BLOCK 512
#define VPT 16    // 16 * 512 = 8192
#define NWAVE 8   // BLOCK/64
#define CAP 1024  // candidate buffer (typical occupancy ~20)

typedef float f32x4 __attribute__((ext_vector_type(4)));

__global__ __launch_bounds__(BLOCK, 8) void sparsemax_kernel(
    const float* __restrict__ z, float* __restrict__ out) {
    const int row = blockIdx.x;
    const f32x4* z4 = (const f32x4*)(z + (size_t)row * ROW_D);
    f32x4* o4 = (f32x4*)(out + (size_t)row * ROW_D);
    const int t = threadIdx.x;
    const int lane = t & 63;
    const int wave = t >> 6;

    __shared__ float s_a[NWAVE];
    __shared__ float s_b[NWAVE];
    __shared__ float s_cand[CAP];
    __shared__ int s_cnt;
    __shared__ float s_tau;

    // ---- load row into registers, coalesced nontemporal float4 ----
    float v[VPT];
#pragma unroll
    for (int j = 0; j < VPT / 4; ++j) {
        f32x4 q = __builtin_nontemporal_load(&z4[j * BLOCK + t]);
        v[j * 4 + 0] = q.x;
        v[j * 4 + 1] = q.y;
        v[j * 4 + 2] = q.z;
        v[j * 4 + 3] = q.w;
    }

    // ---- block max reduction ----
    float m = v[0];
#pragma unroll
    for (int j = 1; j < VPT; ++j) m = fmaxf(m, v[j]);
#pragma unroll
    for (int off = 1; off < 64; off <<= 1) m = fmaxf(m, __shfl_xor(m, off, 64));
    if (t == 0) s_cnt = 0;
    if (lane == 0) s_a[wave] = m;
    __syncthreads();
    float rmax = s_a[0];
#pragma unroll
    for (int w = 1; w < NWAVE; ++w) rmax = fmaxf(rmax, s_a[w]);
    const float thr = rmax - 1.0f;  // tau >= thr provably

    // ---- collect candidates > thr ----
#pragma unroll
    for (int j = 0; j < VPT; ++j) {
        if (v[j] > thr) {
            int idx = atomicAdd(&s_cnt, 1);
            if (idx < CAP) s_cand[idx] = v[j];
        }
    }
    __syncthreads();
    const int cnt = s_cnt;  // uniform across block

    float tau;
    if (cnt <= CAP) {
        // ---- wave 0 solves Michelot on the candidate set ----
        if (wave == 0) {
            float S = 0.f, K = 0.f;
            for (int i = lane; i < cnt; i += 64) {
                S += s_cand[i];
                K += 1.f;
            }
#pragma unroll
            for (int off = 1; off < 64; off <<= 1) {
                S += __shfl_xor(S, off, 64);
                K += __shfl_xor(K, off, 64);
            }
            float tl = (S - 1.f) / K;  // <= tau* (Michelot invariant)
            for (int it = 0; it < 64; ++it) {
                float ps = 0.f, pc = 0.f;
                for (int i = lane; i < cnt; i += 64) {
                    float x = s_cand[i];
                    if (x > tl) {
                        ps += x;
                        pc += 1.f;
                    }
                }
#pragma unroll
                for (int off = 1; off < 64; off <<= 1) {
                    ps += __shfl_xor(ps, off, 64);
                    pc += __shfl_xor(pc, off, 64);
                }
                float nt = (ps - 1.f) / pc;
                if (nt == tl) break;  // uniform within wave
                tl = nt;
            }
            if (lane == 0) s_tau = tl;
        }
        __syncthreads();
        tau = s_tau;
    } else {
        // ---- fallback: full-block Michelot (pathological rows) ----
        float s = 0.f;
#pragma unroll
        for (int j = 0; j < VPT; ++j) s += v[j];
#pragma unroll
        for (int off = 1; off < 64; off <<= 1) s += __shfl_xor(s, off, 64);
        if (lane == 0) s_a[wave] = s;
        __syncthreads();
        float S0 = s_a[0];
#pragma unroll
        for (int w = 1; w < NWAVE; ++w) S0 += s_a[w];
        tau = (S0 - 1.0f) / (float)ROW_D;
        for (int it = 0; it < 64; ++it) {
            float ps = 0.f, pc = 0.f;
#pragma unroll
            for (int j = 0; j < VPT; ++j) {
                bool in = v[j] > tau;
                ps += in ? v[j] : 0.f;
                pc += in ? 1.f : 0.f;
            }
#pragma unroll
            for (int off = 1; off < 64; off <<= 1) {
                ps += __shfl_xor(ps, off, 64);
                pc += __shfl_xor(pc, off, 64);
            }
            __syncthreads();
            if (lane == 0) {
                s_a[wave] = ps;
                s_b[wave] = pc;
            }
            __syncthreads();
            float S = 0.f, K = 0.f;
#pragma unroll
            for (int w = 0; w < NWAVE; ++w) {
                S += s_a[w];
                K += s_b[w];
            }
            float nt = (S - 1.0f) / K;
            if (nt == tau) break;
            tau = nt;
        }
    }

    // ---- write w = max(z - tau, 0), nontemporal float4 ----
#pragma unroll
    for (int j = 0; j < VPT / 4; ++j) {
        f32x4 q;
        q.x = fmaxf(v[j * 4 + 0] - tau, 0.f);
        q.y = fmaxf(v[j * 4 + 1] - tau, 0.f);
        q.z = fmaxf(v[j * 4 + 2] - tau, 0.f);
        q.w = fmaxf(v[j * 4 + 3] - tau, 0.f);
        __builtin_nontemporal_store(q, &o4[j * BLOCK + t]);
    }
}

extern "C" void kernel_launch(void* const* d_in, const int* in_sizes, int n_in,
                              void* d_out, int out_size, void* d_ws, size_t ws_size,
                              hipStream_t stream) {
    const float* z = (const float*)d_in[0];
    float* out = (float*)d_out;
    const int rows = out_size / ROW_D;  // 8192
    sparsemax_kernel<<<rows, BLOCK, 0, stream>>>(z, out);
}